// Round 4
// baseline (57269.263 us; speedup 1.0000x reference)
//
#include <hip/hip_runtime.h>
#include <math.h>

#define Tn 256
#define Bn 32
#define Dn 512
#define Hn 512
#define H3n 1536
#define MW 4
#define Ln 2
#define NBLK 256

__device__ __forceinline__ float sigmoidf_(float x){ return 1.f/(1.f+expf(-x)); }
__device__ __forceinline__ float dot4(float4 a, float4 b){ return a.x*b.x + a.y*b.y + a.z*b.z + a.w*b.w; }

// src[K][N] -> dst[N][K]
__global__ void transpose_kn(const float* __restrict__ src, float* __restrict__ dst, int K, int N){
  int idx = blockIdx.x*256 + threadIdx.x;
  if (idx < K*N){ int k = idx/N, n = idx - k*N; dst[(size_t)n*K + k] = src[idx]; }
}

__global__ void gather_rows(const float* __restrict__ tab, const int* __restrict__ ids,
                            float* __restrict__ out, int rows, int dim){
  int idx = blockIdx.x*256 + threadIdx.x;
  if (idx < rows*dim){ int r = idx/dim, c = idx - r*dim; out[idx] = tab[(size_t)ids[r]*dim + c]; }
}

__global__ void copy_f32(const float* __restrict__ s, float* __restrict__ d, int n){
  for (int i = blockIdx.x*256 + threadIdx.x; i < n; i += gridDim.x*256) d[i] = s[i];
}

__global__ void zero_ints(int* p, int n){
  int i = blockIdx.x*256 + threadIdx.x; if (i < n) p[i] = 0;
}

// C[M][N] = A[M][K] @ B[K][N] (+ bias[N]);  M%64==0, N%64==0, K%32==0
__global__ __launch_bounds__(256) void gemm_f32(const float* __restrict__ A,
    const float* __restrict__ Bm, const float* __restrict__ bias,
    float* __restrict__ C, int M, int N, int K){
  __shared__ float As[32][65];
  __shared__ float Bs[32][64];
  int nbx = N >> 6;
  int bx = blockIdx.x % nbx, by = blockIdx.x / nbx;
  int row0 = by << 6, col0 = bx << 6;
  int tid = threadIdx.x;
  int tx = tid & 15, ty = tid >> 4;
  float acc[4][4] = {};
  for (int k0 = 0; k0 < K; k0 += 32){
#pragma unroll
    for (int i = 0; i < 8; ++i){
      int idx = tid + (i<<8);
      int m = idx >> 5, k = idx & 31;
      As[k][m] = A[(size_t)(row0+m)*K + k0 + k];
    }
#pragma unroll
    for (int i = 0; i < 8; ++i){
      int idx = tid + (i<<8);
      int k = idx >> 6, n = idx & 63;
      Bs[k][n] = Bm[(size_t)(k0+k)*N + col0 + n];
    }
    __syncthreads();
#pragma unroll
    for (int k = 0; k < 32; ++k){
      float4 b4 = *reinterpret_cast<const float4*>(&Bs[k][tx<<2]);
#pragma unroll
      for (int i = 0; i < 4; ++i){
        float a = As[k][(ty<<2)+i];
        acc[i][0] += a*b4.x; acc[i][1] += a*b4.y; acc[i][2] += a*b4.z; acc[i][3] += a*b4.w;
      }
    }
    __syncthreads();
  }
#pragma unroll
  for (int i = 0; i < 4; ++i){
    int r = row0 + (ty<<2) + i;
#pragma unroll
    for (int jj = 0; jj < 4; ++jj){
      int cc = col0 + (tx<<2) + jj;
      float v = acc[i][jj];
      if (bias) v += bias[cc];
      C[(size_t)r*N + cc] = v;
    }
  }
}

// Two-level epoch grid barrier. cnt_l: 8 counters padded to 32 ints each; cnt_g: 1.
__device__ __forceinline__ void gbar(int* cnt_l, int* cnt_g, int ep){
  __threadfence();                 // release: make this thread's writes agent-visible
  __syncthreads();
  if (threadIdx.x == 0){
    int grp = blockIdx.x & 7;
    int v = atomicAdd(&cnt_l[grp << 5], 1);            // device-scope
    if (v == 32*(ep+1) - 1)
      atomicAdd(cnt_g, 1);
    while (__hip_atomic_load(cnt_g, __ATOMIC_ACQUIRE, __HIP_MEMORY_SCOPE_AGENT) < 8*(ep+1))
      __builtin_amdgcn_s_sleep(2);
  }
  __syncthreads();
  __threadfence();                 // acquire side: invalidate stale cached lines
}

// Persistent lattice-LSTM layer: all 256 steps in one launch.
// 256 blocks x 256 threads. Block owns 4 j x 16 b; weight slice cached in LDS.
// Thread: b = b0 + (tid&15); r = tid>>4; j = j0 + (r>>2); l = r&3 (k-slice of 128).
__global__ __launch_bounds__(256) void lattice_persist(
    const float* __restrict__ xi, const float* __restrict__ xa,
    const float* __restrict__ WhhT, const float* __restrict__ aWhhT,
    const float* __restrict__ WwhhT,
    const float* __restrict__ wiw, const float* __restrict__ bw,
    const int* __restrict__ wvalid,
    const float* __restrict__ h0l, const float* __restrict__ c0l,
    float* __restrict__ hbuf,          // [2][B][H]
    float* __restrict__ wc,            // [8][MW][B][H] ring
    float* __restrict__ out_t0,        // out_all[li]: [T][B][H]
    float* __restrict__ hid_h, float* __restrict__ hid_c,
    int* __restrict__ cnt_l, int* __restrict__ cnt_g)
{
  __shared__ __align__(16) float ws_hh[3][4][Hn];   // 24KB
  __shared__ __align__(16) float ws_a [4][Hn];      // 8KB
  __shared__ __align__(16) float ws_w [3][4][Hn];   // 24KB

  const int blk = blockIdx.x;
  const int bg  = blk & 1;
  const int jc  = blk >> 1;
  const int j0  = jc << 2;
  const int b0  = bg << 4;
  const int tid = threadIdx.x;
  const int b_l = tid & 15;
  const int r   = tid >> 4;
  const int j_l = r >> 2;
  const int l   = r & 3;
  const int b   = b0 + b_l;
  const int j   = j0 + j_l;
  const int bj  = (b << 9) + j;

  for (int i = tid; i < 3*4*Hn; i += 256){
    int g = i / (4*Hn); int rem = i - g*(4*Hn); int jj = rem >> 9; int k = rem & 511;
    ws_hh[g][jj][k] = WhhT [((size_t)(g*Hn + j0 + jj) << 9) + k];
    ws_w [g][jj][k] = WwhhT[((size_t)(g*Hn + j0 + jj) << 9) + k];
  }
  for (int i = tid; i < 4*Hn; i += 256){
    int jj = i >> 9; int k = i & 511;
    ws_a[jj][k] = aWhhT[((size_t)(j0 + jj) << 9) + k];
  }
  __syncthreads();

  const float4* wsi4 = reinterpret_cast<const float4*>(&ws_hh[0][j_l][0]) + (l << 5);
  const float4* wso4 = reinterpret_cast<const float4*>(&ws_hh[1][j_l][0]) + (l << 5);
  const float4* wsg4 = reinterpret_cast<const float4*>(&ws_hh[2][j_l][0]) + (l << 5);
  const float4* wsa4 = reinterpret_cast<const float4*>(&ws_a[j_l][0])     + (l << 5);
  const float4* wwi4 = reinterpret_cast<const float4*>(&ws_w[0][j_l][0])  + (l << 5);
  const float4* wwf4 = reinterpret_cast<const float4*>(&ws_w[1][j_l][0])  + (l << 5);
  const float4* wwg4 = reinterpret_cast<const float4*>(&ws_w[2][j_l][0])  + (l << 5);

  float c_reg = c0l[bj];   // live on l==0 lanes
  int ep = 0;

  for (int t = 0; t < Tn; ++t){
    const float* hprev = (t == 0) ? h0l : (hbuf + ((t-1)&1)*(Bn*Hn));
    float* hcur = hbuf + (t&1)*(Bn*Hn);

    int vm0 = (t >= 1) ? wvalid[(t-1)*MW + 0] : 0;
    int vm1 = (t >= 2) ? wvalid[(t-2)*MW + 1] : 0;
    int vm2 = (t >= 3) ? wvalid[(t-3)*MW + 2] : 0;
    int vm3 = (t >= 4) ? wvalid[(t-4)*MW + 3] : 0;
    int any = vm0 | vm1 | vm2 | vm3;

    // ---- phase A: char cell ----
    const float4* hp4 = reinterpret_cast<const float4*>(hprev + (b << 9)) + (l << 5);
    float ai = 0.f, ao = 0.f, ag = 0.f;
#pragma unroll 8
    for (int i = 0; i < 32; ++i){
      float4 h4 = hp4[i];
      ai += dot4(h4, wsi4[i]); ao += dot4(h4, wso4[i]); ag += dot4(h4, wsg4[i]);
    }
    const float* ic0 = wc + ((((t-1)&7)*MW + 0)*(Bn*Hn)) + (b << 9);
    const float* ic1 = wc + ((((t-2)&7)*MW + 1)*(Bn*Hn)) + (b << 9);
    const float* ic2 = wc + ((((t-3)&7)*MW + 2)*(Bn*Hn)) + (b << 9);
    const float* ic3 = wc + ((((t-4)&7)*MW + 3)*(Bn*Hn)) + (b << 9);
    float aa0 = 0.f, aa1 = 0.f, aa2 = 0.f, aa3 = 0.f;
    if (any){
      const float4* p0 = reinterpret_cast<const float4*>(ic0) + (l << 5);
      const float4* p1 = reinterpret_cast<const float4*>(ic1) + (l << 5);
      const float4* p2 = reinterpret_cast<const float4*>(ic2) + (l << 5);
      const float4* p3 = reinterpret_cast<const float4*>(ic3) + (l << 5);
#pragma unroll 8
      for (int i = 0; i < 32; ++i){
        float4 av = wsa4[i];
        if (vm0) aa0 += dot4(p0[i], av);
        if (vm1) aa1 += dot4(p1[i], av);
        if (vm2) aa2 += dot4(p2[i], av);
        if (vm3) aa3 += dot4(p3[i], av);
      }
    }
    // reduce across l (tid bits 4,5 == lane bits 4,5)
    ai += __shfl_xor(ai,16); ai += __shfl_xor(ai,32);
    ao += __shfl_xor(ao,16); ao += __shfl_xor(ao,32);
    ag += __shfl_xor(ag,16); ag += __shfl_xor(ag,32);
    if (any){
      aa0 += __shfl_xor(aa0,16); aa0 += __shfl_xor(aa0,32);
      aa1 += __shfl_xor(aa1,16); aa1 += __shfl_xor(aa1,32);
      aa2 += __shfl_xor(aa2,16); aa2 += __shfl_xor(aa2,32);
      aa3 += __shfl_xor(aa3,16); aa3 += __shfl_xor(aa3,32);
    }
    if (l == 0){
      size_t xoff = (size_t)(t*Bn + b) * H3n;
      float i_ = sigmoidf_(xi[xoff + j] + ai);
      float o_ = sigmoidf_(xi[xoff + 512 + j] + ao);
      float g_ = tanhf(xi[xoff + 1024 + j] + ag);
      float cn;
      if (any){
        float xav = xa[(size_t)(t*Bn + b)*Hn + j];
        float ei = expf(i_);
        float num = ei*g_, den = ei;
        if (vm0){ float ea = expf(sigmoidf_(xav + aa0)); den += ea; num += ea * ic0[j]; }
        if (vm1){ float ea = expf(sigmoidf_(xav + aa1)); den += ea; num += ea * ic1[j]; }
        if (vm2){ float ea = expf(sigmoidf_(xav + aa2)); den += ea; num += ea * ic2[j]; }
        if (vm3){ float ea = expf(sigmoidf_(xav + aa3)); den += ea; num += ea * ic3[j]; }
        cn = num / den;
      } else {
        cn = (1.f - i_)*c_reg + i_*g_;
      }
      float hn = o_ * tanhf(cn);
      c_reg = cn;
      hcur[bj] = hn;
      out_t0[(size_t)t*Bn*Hn + bj] = hn;
      if (t == Tn-1){ hid_h[bj] = hn; hid_c[bj] = cn; }
    }
    gbar(cnt_l, cnt_g, ep); ++ep;

    // ---- phase B: word cells for words starting at t ----
    int v0 = wvalid[t*MW+0], v1 = wvalid[t*MW+1], v2 = wvalid[t*MW+2], v3 = wvalid[t*MW+3];
    if ((v0|v1|v2|v3) && t < Tn-1){
      const float4* h4p = reinterpret_cast<const float4*>(hcur + (b << 9)) + (l << 5);
      float wi_ = 0.f, wf_ = 0.f, wg_ = 0.f;
#pragma unroll 8
      for (int i = 0; i < 32; ++i){
        float4 h4 = h4p[i];
        wi_ += dot4(h4, wwi4[i]); wf_ += dot4(h4, wwf4[i]); wg_ += dot4(h4, wwg4[i]);
      }
      wi_ += __shfl_xor(wi_,16); wi_ += __shfl_xor(wi_,32);
      wf_ += __shfl_xor(wf_,16); wf_ += __shfl_xor(wf_,32);
      wg_ += __shfl_xor(wg_,16); wg_ += __shfl_xor(wg_,32);
      if (l == 0){
        float hwi = wi_ + bw[j];
        float hwf = wf_ + bw[512 + j];
        float hwg = wg_ + bw[1024 + j];
        int ring = (t & 7) * MW;
        const float* wt = wiw + (size_t)(t*MW) * H3n;
        if (v0){ float iw = sigmoidf_(wt[j]+hwi), fw = sigmoidf_(wt[512+j]+hwf), gw = tanhf(wt[1024+j]+hwg);
                 wc[(size_t)(ring+0)*(Bn*Hn) + bj] = fw*c_reg + iw*gw; }
        if (v1){ const float* w1 = wt + H3n;
                 float iw = sigmoidf_(w1[j]+hwi), fw = sigmoidf_(w1[512+j]+hwf), gw = tanhf(w1[1024+j]+hwg);
                 wc[(size_t)(ring+1)*(Bn*Hn) + bj] = fw*c_reg + iw*gw; }
        if (v2){ const float* w2 = wt + 2*H3n;
                 float iw = sigmoidf_(w2[j]+hwi), fw = sigmoidf_(w2[512+j]+hwf), gw = tanhf(w2[1024+j]+hwg);
                 wc[(size_t)(ring+2)*(Bn*Hn) + bj] = fw*c_reg + iw*gw; }
        if (v3){ const float* w3 = wt + 3*H3n;
                 float iw = sigmoidf_(w3[j]+hwi), fw = sigmoidf_(w3[512+j]+hwf), gw = tanhf(w3[1024+j]+hwg);
                 wc[(size_t)(ring+3)*(Bn*Hn) + bj] = fw*c_reg + iw*gw; }
      }
    }
    gbar(cnt_l, cnt_g, ep); ++ep;
  }
}

extern "C" void kernel_launch(void* const* d_in, const int* in_sizes, int n_in,
                              void* d_out, int out_size, void* d_ws, size_t ws_size,
                              hipStream_t stream){
  const float* inputs     = (const float*)d_in[0];
  const float* h0         = (const float*)d_in[1];
  const float* c0         = (const float*)d_in[2];
  const float* gaz        = (const float*)d_in[3];
  const float* W_ih       = (const float*)d_in[4];
  const float* W_hh       = (const float*)d_in[5];
  const float* bias_b     = (const float*)d_in[6];
  const float* aW_ih      = (const float*)d_in[7];
  const float* aW_hh      = (const float*)d_in[8];
  const float* a_b        = (const float*)d_in[9];
  const float* Ww_ih      = (const float*)d_in[10];
  const float* Ww_hh      = (const float*)d_in[11];
  const float* bw         = (const float*)d_in[12];
  const int*   word_ids   = (const int*)d_in[13];
  const int*   word_valid = (const int*)d_in[14];

  float* out     = (float*)d_out;
  float* out_cur = out;                                   // [T,B,H]
  float* out_hh  = out + (size_t)Tn*Bn*Hn;                // [L,B,H]
  float* out_hc  = out_hh + (size_t)Ln*Bn*Hn;             // [L,B,H]
  float* out_all = out_hc + (size_t)Ln*Bn*Hn;             // [L,T,B,H]

  float* p = (float*)d_ws;
  float* WhhT  = p; p += (size_t)H3n*Hn;
  float* aWhhT = p; p += (size_t)Hn*Hn;
  float* WwhhT = p; p += (size_t)H3n*Hn;
  float* wemb  = p; p += (size_t)Tn*MW*Dn;
  float* wiw   = p; p += (size_t)Tn*MW*H3n;
  float* xi    = p; p += (size_t)Tn*Bn*H3n;
  float* xa    = p; p += (size_t)Tn*Bn*Hn;
  float* hbuf  = p; p += (size_t)2*Bn*Hn;
  float* wc    = p; p += (size_t)8*MW*Bn*Hn;
  int*   cnt   = (int*)p; p += 512;                       // cnt_l[8*32] + cnt_g

  int* cnt_l = cnt;
  int* cnt_g = cnt + 8*32;

  transpose_kn<<<(Hn*H3n+255)/256, 256, 0, stream>>>(W_hh,  WhhT,  Hn, H3n);
  transpose_kn<<<(Hn*Hn +255)/256, 256, 0, stream>>>(aW_hh, aWhhT, Hn, Hn);
  transpose_kn<<<(Hn*H3n+255)/256, 256, 0, stream>>>(Ww_hh, WwhhT, Hn, H3n);
  gather_rows<<<(Tn*MW*Dn+255)/256, 256, 0, stream>>>(gaz, word_ids, wemb, Tn*MW, Dn);
  gemm_f32<<<(Tn*MW/64)*(H3n/64), 256, 0, stream>>>(wemb, Ww_ih, nullptr, wiw, Tn*MW, H3n, Dn);

  for (int li = 0; li < Ln; ++li){
    const float* cur = (li == 0) ? inputs : out_all;      // layer-1 input = layer-0 outputs
    gemm_f32<<<(Tn*Bn/64)*(H3n/64), 256, 0, stream>>>(cur, W_ih, bias_b, xi, Tn*Bn, H3n, Dn);
    gemm_f32<<<(Tn*Bn/64)*(Hn/64),  256, 0, stream>>>(cur, aW_ih, a_b,   xa, Tn*Bn, Hn,  Dn);
    zero_ints<<<2, 256, 0, stream>>>(cnt, 512);
    lattice_persist<<<NBLK, 256, 0, stream>>>(
        xi, xa, WhhT, aWhhT, WwhhT, wiw, bw, word_valid,
        h0 + (size_t)li*Bn*Hn, c0 + (size_t)li*Bn*Hn,
        hbuf, wc,
        out_all + (size_t)li*Tn*Bn*Hn,
        out_hh + (size_t)li*Bn*Hn, out_hc + (size_t)li*Bn*Hn,
        cnt_l, cnt_g);
  }
  copy_f32<<<2048, 256, 0, stream>>>(out_all + (size_t)Tn*Bn*Hn, out_cur, Tn*Bn*Hn);
}

// Round 5
// 19721.190 us; speedup vs baseline: 2.9039x; 2.9039x over previous
//
#include <hip/hip_runtime.h>
#include <math.h>

#define Tn 256
#define Bn 32
#define Dn 512
#define Hn 512
#define H3n 1536
#define MW 4
#define Ln 2
#define NBLK 256

__device__ __forceinline__ float sigmoidf_(float x){ return 1.f/(1.f+expf(-x)); }
__device__ __forceinline__ float dot4(float4 a, float4 b){ return a.x*b.x + a.y*b.y + a.z*b.z + a.w*b.w; }

// src[K][N] -> dst[N][K]
__global__ void transpose_kn(const float* __restrict__ src, float* __restrict__ dst, int K, int N){
  int idx = blockIdx.x*256 + threadIdx.x;
  if (idx < K*N){ int k = idx/N, n = idx - k*N; dst[(size_t)n*K + k] = src[idx]; }
}

__global__ void gather_rows(const float* __restrict__ tab, const int* __restrict__ ids,
                            float* __restrict__ out, int rows, int dim){
  int idx = blockIdx.x*256 + threadIdx.x;
  if (idx < rows*dim){ int r = idx/dim, c = idx - r*dim; out[idx] = tab[(size_t)ids[r]*dim + c]; }
}

__global__ void copy_f32(const float* __restrict__ s, float* __restrict__ d, int n){
  for (int i = blockIdx.x*256 + threadIdx.x; i < n; i += gridDim.x*256) d[i] = s[i];
}

__global__ void zero_ints(int* p, int n){
  int i = blockIdx.x*256 + threadIdx.x; if (i < n) p[i] = 0;
}

// C[M][N] = A[M][K] @ B[K][N] (+ bias[N]);  M%64==0, N%64==0, K%32==0
__global__ __launch_bounds__(256) void gemm_f32(const float* __restrict__ A,
    const float* __restrict__ Bm, const float* __restrict__ bias,
    float* __restrict__ C, int M, int N, int K){
  __shared__ float As[32][65];
  __shared__ float Bs[32][64];
  int nbx = N >> 6;
  int bx = blockIdx.x % nbx, by = blockIdx.x / nbx;
  int row0 = by << 6, col0 = bx << 6;
  int tid = threadIdx.x;
  int tx = tid & 15, ty = tid >> 4;
  float acc[4][4] = {};
  for (int k0 = 0; k0 < K; k0 += 32){
#pragma unroll
    for (int i = 0; i < 8; ++i){
      int idx = tid + (i<<8);
      int m = idx >> 5, k = idx & 31;
      As[k][m] = A[(size_t)(row0+m)*K + k0 + k];
    }
#pragma unroll
    for (int i = 0; i < 8; ++i){
      int idx = tid + (i<<8);
      int k = idx >> 6, n = idx & 63;
      Bs[k][n] = Bm[(size_t)(k0+k)*N + col0 + n];
    }
    __syncthreads();
#pragma unroll
    for (int k = 0; k < 32; ++k){
      float4 b4 = *reinterpret_cast<const float4*>(&Bs[k][tx<<2]);
#pragma unroll
      for (int i = 0; i < 4; ++i){
        float a = As[k][(ty<<2)+i];
        acc[i][0] += a*b4.x; acc[i][1] += a*b4.y; acc[i][2] += a*b4.z; acc[i][3] += a*b4.w;
      }
    }
    __syncthreads();
  }
#pragma unroll
  for (int i = 0; i < 4; ++i){
    int r = row0 + (ty<<2) + i;
#pragma unroll
    for (int jj = 0; jj < 4; ++jj){
      int cc = col0 + (tx<<2) + jj;
      float v = acc[i][jj];
      if (bias) v += bias[cc];
      C[(size_t)r*N + cc] = v;
    }
  }
}

// Two-level epoch grid barrier. One release-add + relaxed poll + one acquire
// fence PER BLOCK (thread 0 only). __syncthreads drains vmcnt before entry.
__device__ __forceinline__ void gbar(int* cnt_l, int* cnt_g, int ep){
  __syncthreads();   // emits s_waitcnt vmcnt(0) lgkmcnt(0); all block writes are in L2
  if (threadIdx.x == 0){
    int grp = blockIdx.x & 7;
    // release semantics: flush this XCD's L2 to coherence point once, then add
    int v = __hip_atomic_fetch_add(&cnt_l[grp << 5], 1, __ATOMIC_RELEASE, __HIP_MEMORY_SCOPE_AGENT);
    if (v == 32*(ep+1) - 1)
      __hip_atomic_fetch_add(cnt_g, 1, __ATOMIC_RELEASE, __HIP_MEMORY_SCOPE_AGENT);
    // RELAXED poll: plain coherent load, no per-iteration cache invalidate
    while (__hip_atomic_load(cnt_g, __ATOMIC_RELAXED, __HIP_MEMORY_SCOPE_AGENT) < 8*(ep+1))
      __builtin_amdgcn_s_sleep(4);
    // acquire once: invalidate stale L1/L2 lines before anyone reads
    __builtin_amdgcn_fence(__ATOMIC_ACQUIRE, "agent");
  }
  __syncthreads();
}

// Persistent lattice-LSTM layer: all 256 steps in one launch.
// 256 blocks x 256 threads. Block owns 4 j x 16 b; weight slice cached in LDS.
__global__ __launch_bounds__(256) void lattice_persist(
    const float* __restrict__ xi, const float* __restrict__ xa,
    const float* __restrict__ WhhT, const float* __restrict__ aWhhT,
    const float* __restrict__ WwhhT,
    const float* __restrict__ wiw, const float* __restrict__ bw,
    const int* __restrict__ wvalid,
    const float* __restrict__ h0l, const float* __restrict__ c0l,
    float* __restrict__ hbuf,          // [2][B][H]
    float* __restrict__ wc,            // [8][MW][B][H] ring
    float* __restrict__ out_t0,        // out_all[li]: [T][B][H]
    float* __restrict__ hid_h, float* __restrict__ hid_c,
    int* __restrict__ cnt_l, int* __restrict__ cnt_g)
{
  __shared__ __align__(16) float ws_hh[3][4][Hn];   // 24KB
  __shared__ __align__(16) float ws_a [4][Hn];      // 8KB
  __shared__ __align__(16) float ws_w [3][4][Hn];   // 24KB

  const int blk = blockIdx.x;
  const int bg  = blk & 1;
  const int jc  = blk >> 1;
  const int j0  = jc << 2;
  const int b0  = bg << 4;
  const int tid = threadIdx.x;
  const int b_l = tid & 15;
  const int r   = tid >> 4;
  const int j_l = r >> 2;
  const int l   = r & 3;
  const int b   = b0 + b_l;
  const int j   = j0 + j_l;
  const int bj  = (b << 9) + j;

  for (int i = tid; i < 3*4*Hn; i += 256){
    int g = i / (4*Hn); int rem = i - g*(4*Hn); int jj = rem >> 9; int k = rem & 511;
    ws_hh[g][jj][k] = WhhT [((size_t)(g*Hn + j0 + jj) << 9) + k];
    ws_w [g][jj][k] = WwhhT[((size_t)(g*Hn + j0 + jj) << 9) + k];
  }
  for (int i = tid; i < 4*Hn; i += 256){
    int jj = i >> 9; int k = i & 511;
    ws_a[jj][k] = aWhhT[((size_t)(j0 + jj) << 9) + k];
  }
  __syncthreads();

  const float4* wsi4 = reinterpret_cast<const float4*>(&ws_hh[0][j_l][0]) + (l << 5);
  const float4* wso4 = reinterpret_cast<const float4*>(&ws_hh[1][j_l][0]) + (l << 5);
  const float4* wsg4 = reinterpret_cast<const float4*>(&ws_hh[2][j_l][0]) + (l << 5);
  const float4* wsa4 = reinterpret_cast<const float4*>(&ws_a[j_l][0])     + (l << 5);
  const float4* wwi4 = reinterpret_cast<const float4*>(&ws_w[0][j_l][0])  + (l << 5);
  const float4* wwf4 = reinterpret_cast<const float4*>(&ws_w[1][j_l][0])  + (l << 5);
  const float4* wwg4 = reinterpret_cast<const float4*>(&ws_w[2][j_l][0])  + (l << 5);

  float c_reg = c0l[bj];   // live on l==0 lanes
  int ep = 0;

  for (int t = 0; t < Tn; ++t){
    const float* hprev = (t == 0) ? h0l : (hbuf + ((t-1)&1)*(Bn*Hn));
    float* hcur = hbuf + (t&1)*(Bn*Hn);

    int vm0 = (t >= 1) ? wvalid[(t-1)*MW + 0] : 0;
    int vm1 = (t >= 2) ? wvalid[(t-2)*MW + 1] : 0;
    int vm2 = (t >= 3) ? wvalid[(t-3)*MW + 2] : 0;
    int vm3 = (t >= 4) ? wvalid[(t-4)*MW + 3] : 0;
    int any = vm0 | vm1 | vm2 | vm3;

    // ---- phase A: char cell ----
    const float4* hp4 = reinterpret_cast<const float4*>(hprev + (b << 9)) + (l << 5);
    float ai = 0.f, ao = 0.f, ag = 0.f;
#pragma unroll 8
    for (int i = 0; i < 32; ++i){
      float4 h4 = hp4[i];
      ai += dot4(h4, wsi4[i]); ao += dot4(h4, wso4[i]); ag += dot4(h4, wsg4[i]);
    }
    const float* ic0 = wc + ((((t-1)&7)*MW + 0)*(Bn*Hn)) + (b << 9);
    const float* ic1 = wc + ((((t-2)&7)*MW + 1)*(Bn*Hn)) + (b << 9);
    const float* ic2 = wc + ((((t-3)&7)*MW + 2)*(Bn*Hn)) + (b << 9);
    const float* ic3 = wc + ((((t-4)&7)*MW + 3)*(Bn*Hn)) + (b << 9);
    float aa0 = 0.f, aa1 = 0.f, aa2 = 0.f, aa3 = 0.f;
    if (any){
      const float4* p0 = reinterpret_cast<const float4*>(ic0) + (l << 5);
      const float4* p1 = reinterpret_cast<const float4*>(ic1) + (l << 5);
      const float4* p2 = reinterpret_cast<const float4*>(ic2) + (l << 5);
      const float4* p3 = reinterpret_cast<const float4*>(ic3) + (l << 5);
#pragma unroll 8
      for (int i = 0; i < 32; ++i){
        float4 av = wsa4[i];
        if (vm0) aa0 += dot4(p0[i], av);
        if (vm1) aa1 += dot4(p1[i], av);
        if (vm2) aa2 += dot4(p2[i], av);
        if (vm3) aa3 += dot4(p3[i], av);
      }
    }
    // reduce across l (tid bits 4,5 == lane bits 4,5)
    ai += __shfl_xor(ai,16); ai += __shfl_xor(ai,32);
    ao += __shfl_xor(ao,16); ao += __shfl_xor(ao,32);
    ag += __shfl_xor(ag,16); ag += __shfl_xor(ag,32);
    if (any){
      aa0 += __shfl_xor(aa0,16); aa0 += __shfl_xor(aa0,32);
      aa1 += __shfl_xor(aa1,16); aa1 += __shfl_xor(aa1,32);
      aa2 += __shfl_xor(aa2,16); aa2 += __shfl_xor(aa2,32);
      aa3 += __shfl_xor(aa3,16); aa3 += __shfl_xor(aa3,32);
    }
    if (l == 0){
      size_t xoff = (size_t)(t*Bn + b) * H3n;
      float i_ = sigmoidf_(xi[xoff + j] + ai);
      float o_ = sigmoidf_(xi[xoff + 512 + j] + ao);
      float g_ = tanhf(xi[xoff + 1024 + j] + ag);
      float cn;
      if (any){
        float xav = xa[(size_t)(t*Bn + b)*Hn + j];
        float ei = expf(i_);
        float num = ei*g_, den = ei;
        if (vm0){ float ea = expf(sigmoidf_(xav + aa0)); den += ea; num += ea * ic0[j]; }
        if (vm1){ float ea = expf(sigmoidf_(xav + aa1)); den += ea; num += ea * ic1[j]; }
        if (vm2){ float ea = expf(sigmoidf_(xav + aa2)); den += ea; num += ea * ic2[j]; }
        if (vm3){ float ea = expf(sigmoidf_(xav + aa3)); den += ea; num += ea * ic3[j]; }
        cn = num / den;
      } else {
        cn = (1.f - i_)*c_reg + i_*g_;
      }
      float hn = o_ * tanhf(cn);
      c_reg = cn;
      hcur[bj] = hn;
      out_t0[(size_t)t*Bn*Hn + bj] = hn;
      if (t == Tn-1){ hid_h[bj] = hn; hid_c[bj] = cn; }
    }
    gbar(cnt_l, cnt_g, ep); ++ep;

    // ---- phase B: word cells for words starting at t ----
    int v0 = wvalid[t*MW+0], v1 = wvalid[t*MW+1], v2 = wvalid[t*MW+2], v3 = wvalid[t*MW+3];
    int anyB = (v0|v1|v2|v3) && (t < Tn-1);
    if (anyB){
      const float4* h4p = reinterpret_cast<const float4*>(hcur + (b << 9)) + (l << 5);
      float wi_ = 0.f, wf_ = 0.f, wg_ = 0.f;
#pragma unroll 8
      for (int i = 0; i < 32; ++i){
        float4 h4 = h4p[i];
        wi_ += dot4(h4, wwi4[i]); wf_ += dot4(h4, wwf4[i]); wg_ += dot4(h4, wwg4[i]);
      }
      wi_ += __shfl_xor(wi_,16); wi_ += __shfl_xor(wi_,32);
      wf_ += __shfl_xor(wf_,16); wf_ += __shfl_xor(wf_,32);
      wg_ += __shfl_xor(wg_,16); wg_ += __shfl_xor(wg_,32);
      if (l == 0){
        float hwi = wi_ + bw[j];
        float hwf = wf_ + bw[512 + j];
        float hwg = wg_ + bw[1024 + j];
        int ring = (t & 7) * MW;
        const float* wt = wiw + (size_t)(t*MW) * H3n;
        if (v0){ float iw = sigmoidf_(wt[j]+hwi), fw = sigmoidf_(wt[512+j]+hwf), gw = tanhf(wt[1024+j]+hwg);
                 wc[(size_t)(ring+0)*(Bn*Hn) + bj] = fw*c_reg + iw*gw; }
        if (v1){ const float* w1 = wt + H3n;
                 float iw = sigmoidf_(w1[j]+hwi), fw = sigmoidf_(w1[512+j]+hwf), gw = tanhf(w1[1024+j]+hwg);
                 wc[(size_t)(ring+1)*(Bn*Hn) + bj] = fw*c_reg + iw*gw; }
        if (v2){ const float* w2 = wt + 2*H3n;
                 float iw = sigmoidf_(w2[j]+hwi), fw = sigmoidf_(w2[512+j]+hwf), gw = tanhf(w2[1024+j]+hwg);
                 wc[(size_t)(ring+2)*(Bn*Hn) + bj] = fw*c_reg + iw*gw; }
        if (v3){ const float* w3 = wt + 3*H3n;
                 float iw = sigmoidf_(w3[j]+hwi), fw = sigmoidf_(w3[512+j]+hwf), gw = tanhf(w3[1024+j]+hwg);
                 wc[(size_t)(ring+3)*(Bn*Hn) + bj] = fw*c_reg + iw*gw; }
      }
    }
    // barrier only needed when phase B wrote anything (uniform predicate)
    if (anyB){ gbar(cnt_l, cnt_g, ep); ++ep; }
  }
}

extern "C" void kernel_launch(void* const* d_in, const int* in_sizes, int n_in,
                              void* d_out, int out_size, void* d_ws, size_t ws_size,
                              hipStream_t stream){
  const float* inputs     = (const float*)d_in[0];
  const float* h0         = (const float*)d_in[1];
  const float* c0         = (const float*)d_in[2];
  const float* gaz        = (const float*)d_in[3];
  const float* W_ih       = (const float*)d_in[4];
  const float* W_hh       = (const float*)d_in[5];
  const float* bias_b     = (const float*)d_in[6];
  const float* aW_ih      = (const float*)d_in[7];
  const float* aW_hh      = (const float*)d_in[8];
  const float* a_b        = (const float*)d_in[9];
  const float* Ww_ih      = (const float*)d_in[10];
  const float* Ww_hh      = (const float*)d_in[11];
  const float* bw         = (const float*)d_in[12];
  const int*   word_ids   = (const int*)d_in[13];
  const int*   word_valid = (const int*)d_in[14];

  float* out     = (float*)d_out;
  float* out_cur = out;                                   // [T,B,H]
  float* out_hh  = out + (size_t)Tn*Bn*Hn;                // [L,B,H]
  float* out_hc  = out_hh + (size_t)Ln*Bn*Hn;             // [L,B,H]
  float* out_all = out_hc + (size_t)Ln*Bn*Hn;             // [L,T,B,H]

  float* p = (float*)d_ws;
  float* WhhT  = p; p += (size_t)H3n*Hn;
  float* aWhhT = p; p += (size_t)Hn*Hn;
  float* WwhhT = p; p += (size_t)H3n*Hn;
  float* wemb  = p; p += (size_t)Tn*MW*Dn;
  float* wiw   = p; p += (size_t)Tn*MW*H3n;
  float* xi    = p; p += (size_t)Tn*Bn*H3n;
  float* xa    = p; p += (size_t)Tn*Bn*Hn;
  float* hbuf  = p; p += (size_t)2*Bn*Hn;
  float* wc    = p; p += (size_t)8*MW*Bn*Hn;
  int*   cnt   = (int*)p; p += 512;                       // cnt_l[8*32] + cnt_g

  int* cnt_l = cnt;
  int* cnt_g = cnt + 8*32;

  transpose_kn<<<(Hn*H3n+255)/256, 256, 0, stream>>>(W_hh,  WhhT,  Hn, H3n);
  transpose_kn<<<(Hn*Hn +255)/256, 256, 0, stream>>>(aW_hh, aWhhT, Hn, Hn);
  transpose_kn<<<(Hn*H3n+255)/256, 256, 0, stream>>>(Ww_hh, WwhhT, Hn, H3n);
  gather_rows<<<(Tn*MW*Dn+255)/256, 256, 0, stream>>>(gaz, word_ids, wemb, Tn*MW, Dn);
  gemm_f32<<<(Tn*MW/64)*(H3n/64), 256, 0, stream>>>(wemb, Ww_ih, nullptr, wiw, Tn*MW, H3n, Dn);

  for (int li = 0; li < Ln; ++li){
    const float* cur = (li == 0) ? inputs : out_all;      // layer-1 input = layer-0 outputs
    gemm_f32<<<(Tn*Bn/64)*(H3n/64), 256, 0, stream>>>(cur, W_ih, bias_b, xi, Tn*Bn, H3n, Dn);
    gemm_f32<<<(Tn*Bn/64)*(Hn/64),  256, 0, stream>>>(cur, aW_ih, a_b,   xa, Tn*Bn, Hn,  Dn);
    zero_ints<<<2, 256, 0, stream>>>(cnt, 512);
    lattice_persist<<<NBLK, 256, 0, stream>>>(
        xi, xa, WhhT, aWhhT, WwhhT, wiw, bw, word_valid,
        h0 + (size_t)li*Bn*Hn, c0 + (size_t)li*Bn*Hn,
        hbuf, wc,
        out_all + (size_t)li*Tn*Bn*Hn,
        out_hh + (size_t)li*Bn*Hn, out_hc + (size_t)li*Bn*Hn,
        cnt_l, cnt_g);
  }
  copy_f32<<<2048, 256, 0, stream>>>(out_all + (size_t)Tn*Bn*Hn, out_cur, Tn*Bn*Hn);
}